// Round 1
// baseline (17258.179 us; speedup 1.0000x reference)
//
#include <hip/hip_runtime.h>
#include <math.h>

#define D_MODEL  4096
#define D_HIDDEN 32768
#define BATCH    2048
#define KSEL     128
#define NDEAD    2048

// -------------------- helpers --------------------
__device__ __forceinline__ unsigned int fkey(float f) {
    unsigned int u = __float_as_uint(f);
    return (u & 0x80000000u) ? ~u : (u | 0x80000000u);
}

// -------------------- LayerNorm (fp64 stats) --------------------
__global__ __launch_bounds__(256) void ln_kernel(const float* __restrict__ x,
        double* __restrict__ mu, double* __restrict__ stdv, double* __restrict__ sinv)
{
    const int row = blockIdx.x;
    const int tid = threadIdx.x;
    const float* xr = x + (size_t)row * D_MODEL;
    float xv[16];
#pragma unroll
    for (int i = 0; i < 16; ++i) xv[i] = xr[tid + 256 * i];
    double s = 0.0;
#pragma unroll
    for (int i = 0; i < 16; ++i) s += (double)xv[i];
    __shared__ double red[4];
    __shared__ double sh_mu;
    const int lane = tid & 63, wid = tid >> 6;
#pragma unroll
    for (int off = 32; off > 0; off >>= 1) s += __shfl_down(s, off, 64);
    if (lane == 0) red[wid] = s;
    __syncthreads();
    if (tid == 0) sh_mu = (red[0] + red[1] + red[2] + red[3]) / (double)D_MODEL;
    __syncthreads();
    const double m = sh_mu;
    double s2 = 0.0;
#pragma unroll
    for (int i = 0; i < 16; ++i) { double d = (double)xv[i] - m; s2 += d * d; }
#pragma unroll
    for (int off = 32; off > 0; off >>= 1) s2 += __shfl_down(s2, off, 64);
    __syncthreads();
    if (lane == 0) red[wid] = s2;
    __syncthreads();
    if (tid == 0) {
        double var = (red[0] + red[1] + red[2] + red[3]) / (double)(D_MODEL - 1);
        double sd = sqrt(var);
        mu[row] = m;
        stdv[row] = sd;
        sinv[row] = 1.0 / (sd + 1e-5);
    }
}

// -------------------- dead-mask scan (dual u8/i32 mode) --------------------
__global__ void dead_scan_kernel(const unsigned char* __restrict__ mask8,
                                 int* __restrict__ dead_idx, int* __restrict__ dead_cnt,
                                 const int* __restrict__ num_dead_in, float* __restrict__ out_last)
{
    const int lane = threadIdx.x; // 64 threads, one wave
    int c = 0;
    for (int j = lane; j < D_HIDDEN; j += 64) c += (mask8[j] != 0);
#pragma unroll
    for (int off = 32; off > 0; off >>= 1) c += __shfl_down(c, off, 64);
    const int total_u8 = __shfl(c, 0, 64);
    const bool u8mode = (total_u8 == NDEAD);
    const int* mask32 = (const int*)mask8;
    int cnt = 0;
    for (int base = 0; base < D_HIDDEN; base += 64) {
        const int j = base + lane;
        const bool d = u8mode ? (mask8[j] != 0) : (mask32[j] != 0);
        const unsigned long long b = __ballot(d);
        const int pre = __popcll(b & ((1ull << lane) - 1ull));
        if (d && (cnt + pre) < NDEAD) dead_idx[cnt + pre] = j;
        cnt += __popcll(b);
    }
    const int cc = cnt > NDEAD ? NDEAD : cnt;
    if (lane == 0) {
        *dead_cnt = cc;
        *out_last = (float)(*num_dead_in);
    }
    for (int t = cc + lane; t < NDEAD; t += 64) dead_idx[t] = 0;
}

// -------------------- encoder GEMM, fp64 accumulate --------------------
// pre[m][n] = sum_k ((x[m,k]-mu_m)*sinv_m - b_pre[k]) * w_enc[k][n] + b_enc[n]
__global__ __launch_bounds__(256) void enc_gemm_kernel(
    const float* __restrict__ x, const double* __restrict__ mu, const double* __restrict__ sinv,
    const float* __restrict__ b_pre, const float* __restrict__ w_enc, const float* __restrict__ b_enc,
    float* __restrict__ p32)
{
    __shared__ double As[16][64]; // [kk][m]
    __shared__ double Bs[16][64]; // [kk][n]
    const int tid = threadIdx.x;
    const int n0 = blockIdx.x * 64;
    const int m0 = blockIdx.y * 64;
    const int tx = tid & 15, ty = tid >> 4;
    // A staging coords
    const int am = tid >> 2;
    const int ak = (tid & 3) * 4;
    const int arow = m0 + am;
    const double amu = mu[arow];
    const double ais = sinv[arow];
    const float* xrow = x + (size_t)arow * D_MODEL;
    // B staging coords
    const int bk = tid >> 4;
    const int bn = (tid & 15) * 4;

    double acc[4][4];
#pragma unroll
    for (int i = 0; i < 4; ++i)
#pragma unroll
        for (int j = 0; j < 4; ++j) acc[i][j] = 0.0;

    for (int k0 = 0; k0 < D_MODEL; k0 += 16) {
        const float4 xa = *(const float4*)(xrow + k0 + ak);
        const float4 bp = *(const float4*)(b_pre + k0 + ak);
        As[ak + 0][am] = ((double)xa.x - amu) * ais - (double)bp.x;
        As[ak + 1][am] = ((double)xa.y - amu) * ais - (double)bp.y;
        As[ak + 2][am] = ((double)xa.z - amu) * ais - (double)bp.z;
        As[ak + 3][am] = ((double)xa.w - amu) * ais - (double)bp.w;
        const float4 wb = *(const float4*)(w_enc + (size_t)(k0 + bk) * D_HIDDEN + n0 + bn);
        Bs[bk][bn + 0] = (double)wb.x;
        Bs[bk][bn + 1] = (double)wb.y;
        Bs[bk][bn + 2] = (double)wb.z;
        Bs[bk][bn + 3] = (double)wb.w;
        __syncthreads();
#pragma unroll
        for (int kk = 0; kk < 16; ++kk) {
            double a[4], b[4];
#pragma unroll
            for (int i = 0; i < 4; ++i) a[i] = As[kk][ty * 4 + i];
#pragma unroll
            for (int j = 0; j < 4; ++j) b[j] = Bs[kk][tx * 4 + j];
#pragma unroll
            for (int i = 0; i < 4; ++i)
#pragma unroll
                for (int j = 0; j < 4; ++j) acc[i][j] += a[i] * b[j];
        }
        __syncthreads();
    }
    const float4 be = *(const float4*)(b_enc + n0 + tx * 4);
    const double be4[4] = {(double)be.x, (double)be.y, (double)be.z, (double)be.w};
#pragma unroll
    for (int i = 0; i < 4; ++i) {
        const int m = m0 + ty * 4 + i;
        float4 o;
        o.x = (float)(acc[i][0] + be4[0]);
        o.y = (float)(acc[i][1] + be4[1]);
        o.z = (float)(acc[i][2] + be4[2]);
        o.w = (float)(acc[i][3] + be4[3]);
        *(float4*)(p32 + (size_t)m * D_HIDDEN + n0 + tx * 4) = o;
    }
}

// -------------------- per-row top-128 radix select (exact fp64 tie-break) --------------------
__global__ __launch_bounds__(256) void topk_kernel(
    const float* __restrict__ p32,
    const float* __restrict__ x, const double* __restrict__ mu, const double* __restrict__ sinv,
    const float* __restrict__ b_pre, const float* __restrict__ w_enc, const float* __restrict__ b_enc,
    int* __restrict__ topk_idx, float* __restrict__ topk_val)
{
    const int row = blockIdx.x;
    const int tid = threadIdx.x;
    const float* pr = p32 + (size_t)row * D_HIDDEN;

    __shared__ unsigned int hist[256];
    __shared__ unsigned int sh_prefix, sh_remaining;
    __shared__ int sh_sel, sh_tiecnt;
    __shared__ int tie_idx[64];
    __shared__ double tie_val[64];
    __shared__ unsigned char tie_sel[64];
    __shared__ double red[256];

    if (tid == 0) { sh_prefix = 0u; sh_remaining = KSEL; }

    for (int p = 0; p < 4; ++p) {
        const int shift = 24 - 8 * p;
        hist[tid] = 0u;
        __syncthreads();
        const unsigned int prefix = sh_prefix;
        const unsigned int maskhi = (p == 0) ? 0u : (0xFFFFFFFFu << (shift + 8));
        for (int j = tid; j < D_HIDDEN; j += 256) {
            const unsigned int key = fkey(pr[j]);
            if (((key ^ prefix) & maskhi) == 0u)
                atomicAdd(&hist[(key >> shift) & 255u], 1u);
        }
        __syncthreads();
        if (tid == 0) {
            unsigned int cum = 0, rem = sh_remaining;
            const unsigned int pf = sh_prefix;
            for (int d = 255; d >= 0; --d) {
                const unsigned int c = hist[d];
                if (cum + c >= rem) {
                    sh_prefix = pf | ((unsigned int)d << shift);
                    sh_remaining = rem - cum;
                    break;
                }
                cum += c;
            }
        }
        __syncthreads();
    }
    const unsigned int kth = sh_prefix;
    const int R = (int)sh_remaining;
    if (tid == 0) { sh_sel = 0; sh_tiecnt = 0; }
    __syncthreads();

    int* oidx = topk_idx + row * KSEL;
    float* oval = topk_val + row * KSEL;
    for (int j = tid; j < D_HIDDEN; j += 256) {
        const float v = pr[j];
        const unsigned int key = fkey(v);
        if (key > kth) {
            const int pos = atomicAdd(&sh_sel, 1);
            oidx[pos] = j;
            oval[pos] = v > 0.f ? v : 0.f;
        } else if (key == kth) {
            const int t = atomicAdd(&sh_tiecnt, 1);
            if (t < 64) tie_idx[t] = j;
        }
    }
    __syncthreads();
    const int G = sh_sel;
    const int T = sh_tiecnt;

    if (T == R) {
        if (tid < T) {
            const float pv = pr[tie_idx[tid]];
            oidx[G + tid] = tie_idx[tid];
            oval[G + tid] = pv > 0.f ? pv : 0.f;
        }
        return;
    }
    // rare: more ties than slots -> exact fp64 recompute & rank
    const int TT = T > 64 ? 64 : T;
    const double m_ = mu[row], si = sinv[row];
    const float* xr = x + (size_t)row * D_MODEL;
    for (int t = 0; t < TT; ++t) {
        const int col = tie_idx[t];
        double s = 0.0;
        for (int k = tid; k < D_MODEL; k += 256) {
            const double a = ((double)xr[k] - m_) * si - (double)b_pre[k];
            s += a * (double)w_enc[(size_t)k * D_HIDDEN + col];
        }
        red[tid] = s;
        __syncthreads();
        for (int off = 128; off > 0; off >>= 1) {
            if (tid < off) red[tid] += red[tid + off];
            __syncthreads();
        }
        if (tid == 0) tie_val[t] = red[0] + (double)b_enc[col];
        __syncthreads();
    }
    if (tid == 0) {
        for (int t = 0; t < TT; ++t) tie_sel[t] = 0;
        const int take = R < TT ? R : TT;
        for (int r = 0; r < take; ++r) {
            int best = -1;
            for (int t = 0; t < TT; ++t) {
                if (tie_sel[t]) continue;
                if (best < 0 || tie_val[t] > tie_val[best] ||
                    (tie_val[t] == tie_val[best] && tie_idx[t] < tie_idx[best])) best = t;
            }
            tie_sel[best] = 1;
            const float pv = pr[tie_idx[best]];
            oidx[G + r] = tie_idx[best];
            oval[G + r] = pv > 0.f ? pv : 0.f;
        }
        for (int r = take; r < R; ++r) { oidx[G + r] = tie_idx[0]; oval[G + r] = 0.f; }
    }
}

// -------------------- sparse decode: recons --------------------
__global__ __launch_bounds__(256) void decode_kernel(
    const int* __restrict__ topk_idx, const float* __restrict__ topk_val,
    const float* __restrict__ w_dec, const float* __restrict__ b_pre,
    const double* __restrict__ mu, const double* __restrict__ stdv,
    float* __restrict__ out0)
{
    const int row = blockIdx.x;
    const int tid = threadIdx.x;
    __shared__ int sidx[KSEL];
    __shared__ float sval[KSEL];
    if (tid < KSEL) {
        sidx[tid] = topk_idx[row * KSEL + tid];
        sval[tid] = topk_val[row * KSEL + tid];
    }
    __syncthreads();
    float4 acc[4];
#pragma unroll
    for (int i = 0; i < 4; ++i) { acc[i].x = 0.f; acc[i].y = 0.f; acc[i].z = 0.f; acc[i].w = 0.f; }
    const int dbase = tid * 16;
    for (int k = 0; k < KSEL; ++k) {
        const float v = sval[k];
        if (v == 0.f) continue;
        const float4* wr = (const float4*)(w_dec + (size_t)sidx[k] * D_MODEL + dbase);
#pragma unroll
        for (int i = 0; i < 4; ++i) {
            const float4 w = wr[i];
            acc[i].x += v * w.x; acc[i].y += v * w.y; acc[i].z += v * w.z; acc[i].w += v * w.w;
        }
    }
    const float st = (float)stdv[row];
    const float mm = (float)mu[row];
    const float4* bp = (const float4*)(b_pre + dbase);
    float4* o = (float4*)(out0 + (size_t)row * D_MODEL + dbase);
#pragma unroll
    for (int i = 0; i < 4; ++i) {
        const float4 b = bp[i];
        float4 r;
        r.x = (acc[i].x + b.x) * st + mm;
        r.y = (acc[i].y + b.y) * st + mm;
        r.z = (acc[i].z + b.z) * st + mm;
        r.w = (acc[i].w + b.w) * st + mm;
        o[i] = r;
    }
}

// -------------------- aux gather: A_dead[r][c] = relu(pre[r][dead_idx[c]]) --------------------
__global__ __launch_bounds__(256) void aux_gather_kernel(
    const float* __restrict__ p32, const int* __restrict__ dead_idx,
    const int* __restrict__ dead_cnt, float* __restrict__ A_dead)
{
    const int gid = blockIdx.x * 256 + threadIdx.x;
    const int r = gid >> 11;
    const int c = gid & 2047;
    float v = 0.f;
    if (c < *dead_cnt) {
        v = p32[(size_t)r * D_HIDDEN + dead_idx[c]];
        v = v > 0.f ? v : 0.f;
    }
    A_dead[gid] = v;
}

// -------------------- aux GEMM: out1 = (A_dead @ w_dec[dead,:] + b_pre)*std + mu --------------------
__global__ __launch_bounds__(256) void aux_gemm_kernel(
    const float* __restrict__ A_dead, const float* __restrict__ w_dec,
    const int* __restrict__ dead_idx, const float* __restrict__ b_pre,
    const double* __restrict__ mu, const double* __restrict__ stdv,
    float* __restrict__ out1)
{
    __shared__ float As[16][64];
    __shared__ float Bs[16][64];
    const int tid = threadIdx.x;
    const int n0 = blockIdx.x * 64;
    const int m0 = blockIdx.y * 64;
    const int tx = tid & 15, ty = tid >> 4;
    const int am = tid >> 2;
    const int ak = (tid & 3) * 4;
    const int bk = tid >> 4;
    const int bn = (tid & 15) * 4;

    float acc[4][4];
#pragma unroll
    for (int i = 0; i < 4; ++i)
#pragma unroll
        for (int j = 0; j < 4; ++j) acc[i][j] = 0.f;

    for (int k0 = 0; k0 < NDEAD; k0 += 16) {
        const float4 a4 = *(const float4*)(A_dead + (size_t)(m0 + am) * NDEAD + k0 + ak);
        As[ak + 0][am] = a4.x;
        As[ak + 1][am] = a4.y;
        As[ak + 2][am] = a4.z;
        As[ak + 3][am] = a4.w;
        const int srow = dead_idx[k0 + bk];
        const float4 b4 = *(const float4*)(w_dec + (size_t)srow * D_MODEL + n0 + bn);
        Bs[bk][bn + 0] = b4.x;
        Bs[bk][bn + 1] = b4.y;
        Bs[bk][bn + 2] = b4.z;
        Bs[bk][bn + 3] = b4.w;
        __syncthreads();
#pragma unroll
        for (int kk = 0; kk < 16; ++kk) {
            float a[4], b[4];
#pragma unroll
            for (int i = 0; i < 4; ++i) a[i] = As[kk][ty * 4 + i];
#pragma unroll
            for (int j = 0; j < 4; ++j) b[j] = Bs[kk][tx * 4 + j];
#pragma unroll
            for (int i = 0; i < 4; ++i)
#pragma unroll
                for (int j = 0; j < 4; ++j) acc[i][j] += a[i] * b[j];
        }
        __syncthreads();
    }
    const float4 bp = *(const float4*)(b_pre + n0 + tx * 4);
#pragma unroll
    for (int i = 0; i < 4; ++i) {
        const int m = m0 + ty * 4 + i;
        const float st = (float)stdv[m];
        const float mm = (float)mu[m];
        float4 o;
        o.x = (acc[i][0] + bp.x) * st + mm;
        o.y = (acc[i][1] + bp.y) * st + mm;
        o.z = (acc[i][2] + bp.z) * st + mm;
        o.w = (acc[i][3] + bp.w) * st + mm;
        *(float4*)(out1 + (size_t)m * D_MODEL + n0 + tx * 4) = o;
    }
}

// -------------------- launch --------------------
extern "C" void kernel_launch(void* const* d_in, const int* in_sizes, int n_in,
                              void* d_out, int out_size, void* d_ws, size_t ws_size,
                              hipStream_t stream)
{
    (void)in_sizes; (void)n_in; (void)out_size; (void)ws_size;
    const float* x      = (const float*)d_in[0];
    const float* w_enc  = (const float*)d_in[1];
    const float* w_dec  = (const float*)d_in[2];
    const float* b_enc  = (const float*)d_in[3];
    const float* b_pre  = (const float*)d_in[4];
    const unsigned char* dead_mask = (const unsigned char*)d_in[5];
    const int* num_dead = (const int*)d_in[6];
    float* out = (float*)d_out;

    char* w = (char*)d_ws;
    float* p32 = (float*)w;       w += (size_t)BATCH * D_HIDDEN * 4;   // 256 MB
    double* mu = (double*)w;      w += (size_t)BATCH * 8;
    double* stdv = (double*)w;    w += (size_t)BATCH * 8;
    double* sinv = (double*)w;    w += (size_t)BATCH * 8;
    int* topk_idx = (int*)w;      w += (size_t)BATCH * KSEL * 4;
    float* topk_val = (float*)w;  w += (size_t)BATCH * KSEL * 4;
    int* dead_idx = (int*)w;      w += (size_t)NDEAD * 4;
    int* dead_cnt = (int*)w;      w += 256;
    float* A_dead = (float*)w;    w += (size_t)BATCH * NDEAD * 4;      // 16 MB

    float* out0 = out;                                   // recons
    float* out1 = out + (size_t)BATCH * D_MODEL;         // auxk
    float* out_last = out + (size_t)2 * BATCH * D_MODEL; // num_dead

    ln_kernel<<<BATCH, 256, 0, stream>>>(x, mu, stdv, sinv);
    dead_scan_kernel<<<1, 64, 0, stream>>>(dead_mask, dead_idx, dead_cnt, num_dead, out_last);
    enc_gemm_kernel<<<dim3(D_HIDDEN / 64, BATCH / 64), 256, 0, stream>>>(
        x, mu, sinv, b_pre, w_enc, b_enc, p32);
    topk_kernel<<<BATCH, 256, 0, stream>>>(p32, x, mu, sinv, b_pre, w_enc, b_enc, topk_idx, topk_val);
    decode_kernel<<<BATCH, 256, 0, stream>>>(topk_idx, topk_val, w_dec, b_pre, mu, stdv, out0);
    aux_gather_kernel<<<(BATCH * NDEAD) / 256, 256, 0, stream>>>(p32, dead_idx, dead_cnt, A_dead);
    aux_gemm_kernel<<<dim3(D_MODEL / 64, BATCH / 64), 256, 0, stream>>>(
        A_dead, w_dec, dead_idx, b_pre, mu, stdv, out1);
}

// Round 2
// 4003.225 us; speedup vs baseline: 4.3111x; 4.3111x over previous
//
#include <hip/hip_runtime.h>
#include <math.h>

#define D_MODEL  4096
#define D_HIDDEN 32768
#define BATCH    2048
#define KSEL     128
#define NDEAD    2048

typedef short s16x8 __attribute__((ext_vector_type(8)));
typedef float f32x4 __attribute__((ext_vector_type(4)));

// -------------------- helpers --------------------
__device__ __forceinline__ unsigned int fkey(float f) {
    unsigned int u = __float_as_uint(f);
    return (u & 0x80000000u) ? ~u : (u | 0x80000000u);
}
__device__ __forceinline__ float unfkey(unsigned int k) {
    unsigned int u = (k & 0x80000000u) ? (k & 0x7FFFFFFFu) : ~k;
    return __uint_as_float(u);
}
__device__ __forceinline__ unsigned short f2bf(float f) {  // RTNE
    unsigned int u = __float_as_uint(f);
    u += 0x7FFFu + ((u >> 16) & 1u);
    return (unsigned short)(u >> 16);
}
__device__ __forceinline__ float bf2f(unsigned short h) {
    return __uint_as_float(((unsigned int)h) << 16);
}
__device__ __forceinline__ void async_copy16(void* lds_dst, const void* gsrc) {
    __builtin_amdgcn_global_load_lds(
        (const __attribute__((address_space(1))) unsigned int*)gsrc,
        (__attribute__((address_space(3))) unsigned int*)lds_dst,
        16, 0, 0);
}

// -------------------- LayerNorm (fp64 stats) --------------------
__global__ __launch_bounds__(256) void ln_kernel(const float* __restrict__ x,
        double* __restrict__ mu, double* __restrict__ stdv, double* __restrict__ sinv)
{
    const int row = blockIdx.x;
    const int tid = threadIdx.x;
    const float* xr = x + (size_t)row * D_MODEL;
    float xv[16];
#pragma unroll
    for (int i = 0; i < 16; ++i) xv[i] = xr[tid + 256 * i];
    double s = 0.0;
#pragma unroll
    for (int i = 0; i < 16; ++i) s += (double)xv[i];
    __shared__ double red[4];
    __shared__ double sh_mu;
    const int lane = tid & 63, wid = tid >> 6;
#pragma unroll
    for (int off = 32; off > 0; off >>= 1) s += __shfl_down(s, off, 64);
    if (lane == 0) red[wid] = s;
    __syncthreads();
    if (tid == 0) sh_mu = (red[0] + red[1] + red[2] + red[3]) / (double)D_MODEL;
    __syncthreads();
    const double m = sh_mu;
    double s2 = 0.0;
#pragma unroll
    for (int i = 0; i < 16; ++i) { double d = (double)xv[i] - m; s2 += d * d; }
#pragma unroll
    for (int off = 32; off > 0; off >>= 1) s2 += __shfl_down(s2, off, 64);
    __syncthreads();
    if (lane == 0) red[wid] = s2;
    __syncthreads();
    if (tid == 0) {
        double var = (red[0] + red[1] + red[2] + red[3]) / (double)(D_MODEL - 1);
        double sd = sqrt(var);
        mu[row] = m;
        stdv[row] = sd;
        sinv[row] = 1.0 / (sd + 1e-5);
    }
}

// -------------------- dead-mask scan --------------------
__global__ void dead_scan_kernel(const unsigned char* __restrict__ mask8,
                                 int* __restrict__ dead_idx, int* __restrict__ dead_cnt,
                                 const int* __restrict__ num_dead_in, float* __restrict__ out_last)
{
    const int lane = threadIdx.x; // 64 threads, one wave
    int c = 0;
    for (int j = lane; j < D_HIDDEN; j += 64) c += (mask8[j] != 0);
#pragma unroll
    for (int off = 32; off > 0; off >>= 1) c += __shfl_down(c, off, 64);
    const int total_u8 = __shfl(c, 0, 64);
    const bool u8mode = (total_u8 == NDEAD);
    const int* mask32 = (const int*)mask8;
    int cnt = 0;
    for (int base = 0; base < D_HIDDEN; base += 64) {
        const int j = base + lane;
        const bool d = u8mode ? (mask8[j] != 0) : (mask32[j] != 0);
        const unsigned long long b = __ballot(d);
        const int pre = __popcll(b & ((1ull << lane) - 1ull));
        if (d && (cnt + pre) < NDEAD) dead_idx[cnt + pre] = j;
        cnt += __popcll(b);
    }
    const int cc = cnt > NDEAD ? NDEAD : cnt;
    if (lane == 0) {
        *dead_cnt = cc;
        *out_last = (float)(*num_dead_in);
    }
    for (int t = cc + lane; t < NDEAD; t += 64) dead_idx[t] = 0;
}

// -------------------- A split: xc -> hi/mid bf16 planes --------------------
__global__ __launch_bounds__(256) void asplit_kernel(
    const float* __restrict__ x, const double* __restrict__ mu, const double* __restrict__ sinv,
    const float* __restrict__ b_pre,
    unsigned short* __restrict__ Ahp, unsigned short* __restrict__ Amp)
{
    const int row = blockIdx.x, tid = threadIdx.x;
    const double m = mu[row], si = sinv[row];
    const float* xr = x + (size_t)row * D_MODEL;
#pragma unroll
    for (int i = 0; i < 4; ++i) {
        const int j = (i * 256 + tid) * 4;
        const float4 xv = *(const float4*)(xr + j);
        const float4 bp = *(const float4*)(b_pre + j);
        float v[4];
        v[0] = (float)(((double)xv.x - m) * si) - bp.x;
        v[1] = (float)(((double)xv.y - m) * si) - bp.y;
        v[2] = (float)(((double)xv.z - m) * si) - bp.z;
        v[3] = (float)(((double)xv.w - m) * si) - bp.w;
        unsigned short h[4], md[4];
#pragma unroll
        for (int e = 0; e < 4; ++e) {
            h[e] = f2bf(v[e]);
            md[e] = f2bf(v[e] - bf2f(h[e]));
        }
        uint2 hw, mw;
        hw.x = (unsigned)h[0] | ((unsigned)h[1] << 16);
        hw.y = (unsigned)h[2] | ((unsigned)h[3] << 16);
        mw.x = (unsigned)md[0] | ((unsigned)md[1] << 16);
        mw.y = (unsigned)md[2] | ((unsigned)md[3] << 16);
        *(uint2*)(Ahp + (size_t)row * D_MODEL + j) = hw;
        *(uint2*)(Amp + (size_t)row * D_MODEL + j) = mw;
    }
}

// -------------------- B split+transpose: w_enc[k][n] -> Bh/Bm[n][k] --------------------
__global__ __launch_bounds__(256) void bsplit_kernel(
    const float* __restrict__ w_enc,
    unsigned short* __restrict__ Bhp, unsigned short* __restrict__ Bmp)
{
    __shared__ float t[32][33];
    const int bk = blockIdx.x * 32;
    const int bn = blockIdx.y * 32;
    const int tid = threadIdx.x;
    const int lr = tid >> 3, lc4 = (tid & 7) * 4;
    const float4 v = *(const float4*)(w_enc + (size_t)(bk + lr) * D_HIDDEN + bn + lc4);
    t[lr][lc4 + 0] = v.x; t[lr][lc4 + 1] = v.y; t[lr][lc4 + 2] = v.z; t[lr][lc4 + 3] = v.w;
    __syncthreads();
    float o[4];
#pragma unroll
    for (int j = 0; j < 4; ++j) o[j] = t[lc4 + j][lr];
    unsigned short h[4], md[4];
#pragma unroll
    for (int e = 0; e < 4; ++e) {
        h[e] = f2bf(o[e]);
        md[e] = f2bf(o[e] - bf2f(h[e]));
    }
    uint2 hw, mw;
    hw.x = (unsigned)h[0] | ((unsigned)h[1] << 16);
    hw.y = (unsigned)h[2] | ((unsigned)h[3] << 16);
    mw.x = (unsigned)md[0] | ((unsigned)md[1] << 16);
    mw.y = (unsigned)md[2] | ((unsigned)md[3] << 16);
    *(uint2*)(Bhp + (size_t)(bn + lr) * D_MODEL + bk + lc4) = hw;
    *(uint2*)(Bmp + (size_t)(bn + lr) * D_MODEL + bk + lc4) = mw;
}

// -------------------- encoder GEMM: split-bf16 MFMA (3 products) --------------------
template<bool PRESPLIT>
__global__ __launch_bounds__(256) void enc_mfma_kernel(
    const unsigned short* __restrict__ Ahp, const unsigned short* __restrict__ Amp,
    const unsigned short* __restrict__ Bhp, const unsigned short* __restrict__ Bmp,
    const float* __restrict__ w_enc, const float* __restrict__ b_enc,
    float* __restrict__ p32)
{
    __shared__ unsigned short lds[4 * 128 * 32];  // planes: Ah, Am, Bh, Bm; [row][32] linear
    const int tid = threadIdx.x;
    const int lane = tid & 63, wid = tid >> 6;
    const int m0 = blockIdx.x * 128;
    const int n0 = blockIdx.y * 128;
    const int wm = (wid >> 1) * 64, wn = (wid & 1) * 64;
    const int fr = lane & 15, kq = lane >> 4;

    f32x4 acc[4][4];
#pragma unroll
    for (int i = 0; i < 4; ++i)
#pragma unroll
        for (int j = 0; j < 4; ++j) acc[i][j] = (f32x4){0.f, 0.f, 0.f, 0.f};

    for (int k0 = 0; k0 < D_MODEL; k0 += 32) {
        if constexpr (PRESPLIT) {
            // wave w stages plane w via global_load_lds (linear LDS, m97 pattern)
            const unsigned short* gp = (wid == 0) ? Ahp : (wid == 1) ? Amp : (wid == 2) ? Bhp : Bmp;
            const int t0 = (wid < 2) ? m0 : n0;
            const unsigned short* src0 = gp + (size_t)(t0 + (lane >> 2)) * D_MODEL + k0 + (lane & 3) * 8;
#pragma unroll
            for (int seg = 0; seg < 8; ++seg) {
                async_copy16(lds + wid * 4096 + seg * 512, src0 + (size_t)seg * 16 * D_MODEL);
            }
        } else {
            // A from pre-split planes (reg-staged)
#pragma unroll
            for (int i = 0; i < 2; ++i) {
                const int f = i * 256 + tid;          // 0..511
                const int r = f >> 2, kk = (f & 3) * 8;
                *(uint4*)(lds + 0 * 4096 + r * 32 + kk) =
                    *(const uint4*)(Ahp + (size_t)(m0 + r) * D_MODEL + k0 + kk);
                *(uint4*)(lds + 1 * 4096 + r * 32 + kk) =
                    *(const uint4*)(Amp + (size_t)(m0 + r) * D_MODEL + k0 + kk);
            }
            // B on the fly: load w_enc[k][n] patch 4k x 4n, split, transpose into LDS
            const int pk = (tid >> 5) * 4, pn = (tid & 31) * 4;
            float4 rr[4];
#pragma unroll
            for (int i = 0; i < 4; ++i)
                rr[i] = *(const float4*)(w_enc + (size_t)(k0 + pk + i) * D_HIDDEN + n0 + pn);
#pragma unroll
            for (int cc = 0; cc < 4; ++cc) {
                unsigned short h[4], md[4];
#pragma unroll
                for (int i = 0; i < 4; ++i) {
                    const float vv = ((const float*)&rr[i])[cc];
                    h[i] = f2bf(vv);
                    md[i] = f2bf(vv - bf2f(h[i]));
                }
                const int rowb = pn + cc;
                uint2 hw, mw;
                hw.x = (unsigned)h[0] | ((unsigned)h[1] << 16);
                hw.y = (unsigned)h[2] | ((unsigned)h[3] << 16);
                mw.x = (unsigned)md[0] | ((unsigned)md[1] << 16);
                mw.y = (unsigned)md[2] | ((unsigned)md[3] << 16);
                *(uint2*)(lds + 2 * 4096 + rowb * 32 + pk) = hw;
                *(uint2*)(lds + 3 * 4096 + rowb * 32 + pk) = mw;
            }
        }
        __syncthreads();

        s16x8 ah[4], am[4], bh[4], bm[4];
#pragma unroll
        for (int i = 0; i < 4; ++i) {
            ah[i] = *(const s16x8*)(lds + 0 * 4096 + (wm + i * 16 + fr) * 32 + kq * 8);
            am[i] = *(const s16x8*)(lds + 1 * 4096 + (wm + i * 16 + fr) * 32 + kq * 8);
            bh[i] = *(const s16x8*)(lds + 2 * 4096 + (wn + i * 16 + fr) * 32 + kq * 8);
            bm[i] = *(const s16x8*)(lds + 3 * 4096 + (wn + i * 16 + fr) * 32 + kq * 8);
        }
#pragma unroll
        for (int mi = 0; mi < 4; ++mi)
#pragma unroll
            for (int ni = 0; ni < 4; ++ni) {
                acc[mi][ni] = __builtin_amdgcn_mfma_f32_16x16x32_bf16(ah[mi], bh[ni], acc[mi][ni], 0, 0, 0);
                acc[mi][ni] = __builtin_amdgcn_mfma_f32_16x16x32_bf16(ah[mi], bm[ni], acc[mi][ni], 0, 0, 0);
                acc[mi][ni] = __builtin_amdgcn_mfma_f32_16x16x32_bf16(am[mi], bh[ni], acc[mi][ni], 0, 0, 0);
            }
        __syncthreads();
    }
    // epilogue: +b_enc, store fp32
#pragma unroll
    for (int ni = 0; ni < 4; ++ni) {
        const int col = n0 + wn + ni * 16 + fr;
        const float be = b_enc[col];
#pragma unroll
        for (int mi = 0; mi < 4; ++mi) {
            const int rb = m0 + wm + mi * 16 + kq * 4;
            float* dst = p32 + (size_t)rb * D_HIDDEN + col;
            dst[0]                = acc[mi][ni][0] + be;
            dst[D_HIDDEN]         = acc[mi][ni][1] + be;
            dst[2 * (size_t)D_HIDDEN] = acc[mi][ni][2] + be;
            dst[3 * (size_t)D_HIDDEN] = acc[mi][ni][3] + be;
        }
    }
}

// -------------------- per-row top-128: radix select + band-exact refinement --------------------
__global__ __launch_bounds__(256) void topk_kernel(
    const float* __restrict__ p32,
    const float* __restrict__ x, const double* __restrict__ mu, const double* __restrict__ sinv,
    const float* __restrict__ b_pre, const float* __restrict__ w_enc, const float* __restrict__ b_enc,
    int* __restrict__ topk_idx, float* __restrict__ topk_val)
{
    const int row = blockIdx.x;
    const int tid = threadIdx.x;
    const float* pr = p32 + (size_t)row * D_HIDDEN;

    __shared__ unsigned int hist[256];
    __shared__ unsigned int sh_prefix, sh_remaining;
    __shared__ int sh_sel, sh_tiecnt;
    __shared__ int tie_idx[128];
    __shared__ double tie_val[128];
    __shared__ unsigned char tie_sel[128];
    __shared__ double red[256];

    if (tid == 0) { sh_prefix = 0u; sh_remaining = KSEL; }

    for (int p = 0; p < 4; ++p) {
        const int shift = 24 - 8 * p;
        hist[tid] = 0u;
        __syncthreads();
        const unsigned int prefix = sh_prefix;
        const unsigned int maskhi = (p == 0) ? 0u : (0xFFFFFFFFu << (shift + 8));
        for (int j = tid; j < D_HIDDEN; j += 256) {
            const unsigned int key = fkey(pr[j]);
            if (((key ^ prefix) & maskhi) == 0u)
                atomicAdd(&hist[(key >> shift) & 255u], 1u);
        }
        __syncthreads();
        if (tid == 0) {
            unsigned int cum = 0, rem = sh_remaining;
            const unsigned int pf = sh_prefix;
            for (int d = 255; d >= 0; --d) {
                const unsigned int c = hist[d];
                if (cum + c >= rem) {
                    sh_prefix = pf | ((unsigned int)d << shift);
                    sh_remaining = rem - cum;
                    break;
                }
                cum += c;
            }
        }
        __syncthreads();
    }
    const float c = unfkey(sh_prefix);
    const float dlt = 5e-4f;
    const float hiT = c + dlt, loT = c - dlt;
    if (tid == 0) { sh_sel = 0; sh_tiecnt = 0; }
    __syncthreads();

    int* oidx = topk_idx + row * KSEL;
    float* oval = topk_val + row * KSEL;
    for (int j = tid; j < D_HIDDEN; j += 256) {
        const float v = pr[j];
        if (v > hiT) {
            const int pos = atomicAdd(&sh_sel, 1);
            oidx[pos] = j;
            oval[pos] = v > 0.f ? v : 0.f;
        } else if (v >= loT) {
            const int t = atomicAdd(&sh_tiecnt, 1);
            if (t < 128) tie_idx[t] = j;
        }
    }
    __syncthreads();
    const int G = sh_sel;
    int T = sh_tiecnt; if (T > 128) T = 128;
    const int R = KSEL - G;  // needed from candidates (>=1, <=T in practice)

    // exact fp64 recompute of all candidates
    const double m_ = mu[row], si = sinv[row];
    const float* xr = x + (size_t)row * D_MODEL;
    for (int t = 0; t < T; ++t) {
        const int col = tie_idx[t];
        double s = 0.0;
        for (int k = tid; k < D_MODEL; k += 256) {
            const double a = ((double)xr[k] - m_) * si - (double)b_pre[k];
            s += a * (double)w_enc[(size_t)k * D_HIDDEN + col];
        }
        red[tid] = s;
        __syncthreads();
        for (int off = 128; off > 0; off >>= 1) {
            if (tid < off) red[tid] += red[tid + off];
            __syncthreads();
        }
        if (tid == 0) tie_val[t] = red[0] + (double)b_enc[col];
        __syncthreads();
    }
    if (tid == 0) {
        for (int t = 0; t < T; ++t) tie_sel[t] = 0;
        const int take = R < T ? R : T;
        for (int r = 0; r < take; ++r) {
            int best = -1;
            for (int t = 0; t < T; ++t) {
                if (tie_sel[t]) continue;
                if (best < 0 || tie_val[t] > tie_val[best] ||
                    (tie_val[t] == tie_val[best] && tie_idx[t] < tie_idx[best])) best = t;
            }
            tie_sel[best] = 1;
            const float ev = (float)tie_val[best];
            oidx[G + r] = tie_idx[best];
            oval[G + r] = ev > 0.f ? ev : 0.f;
        }
        for (int r = take; r < R; ++r) { oidx[G + r] = tie_idx[0]; oval[G + r] = 0.f; }
    }
}

// -------------------- sparse decode: recons --------------------
__global__ __launch_bounds__(256) void decode_kernel(
    const int* __restrict__ topk_idx, const float* __restrict__ topk_val,
    const float* __restrict__ w_dec, const float* __restrict__ b_pre,
    const double* __restrict__ mu, const double* __restrict__ stdv,
    float* __restrict__ out0)
{
    const int row = blockIdx.x;
    const int tid = threadIdx.x;
    __shared__ int sidx[KSEL];
    __shared__ float sval[KSEL];
    if (tid < KSEL) {
        sidx[tid] = topk_idx[row * KSEL + tid];
        sval[tid] = topk_val[row * KSEL + tid];
    }
    __syncthreads();
    float4 acc[4];
#pragma unroll
    for (int i = 0; i < 4; ++i) { acc[i].x = 0.f; acc[i].y = 0.f; acc[i].z = 0.f; acc[i].w = 0.f; }
    const int dbase = tid * 16;
    for (int k = 0; k < KSEL; ++k) {
        const float v = sval[k];
        if (v == 0.f) continue;
        const float4* wr = (const float4*)(w_dec + (size_t)sidx[k] * D_MODEL + dbase);
#pragma unroll
        for (int i = 0; i < 4; ++i) {
            const float4 w = wr[i];
            acc[i].x += v * w.x; acc[i].y += v * w.y; acc[i].z += v * w.z; acc[i].w += v * w.w;
        }
    }
    const float st = (float)stdv[row];
    const float mm = (float)mu[row];
    const float4* bp = (const float4*)(b_pre + dbase);
    float4* o = (float4*)(out0 + (size_t)row * D_MODEL + dbase);
#pragma unroll
    for (int i = 0; i < 4; ++i) {
        const float4 b = bp[i];
        float4 r;
        r.x = (acc[i].x + b.x) * st + mm;
        r.y = (acc[i].y + b.y) * st + mm;
        r.z = (acc[i].z + b.z) * st + mm;
        r.w = (acc[i].w + b.w) * st + mm;
        o[i] = r;
    }
}

// -------------------- aux gather --------------------
__global__ __launch_bounds__(256) void aux_gather_kernel(
    const float* __restrict__ p32, const int* __restrict__ dead_idx,
    const int* __restrict__ dead_cnt, float* __restrict__ A_dead)
{
    const int gid = blockIdx.x * 256 + threadIdx.x;
    const int r = gid >> 11;
    const int c = gid & 2047;
    float v = 0.f;
    if (c < *dead_cnt) {
        v = p32[(size_t)r * D_HIDDEN + dead_idx[c]];
        v = v > 0.f ? v : 0.f;
    }
    A_dead[gid] = v;
}

// -------------------- aux GEMM (fp32) --------------------
__global__ __launch_bounds__(256) void aux_gemm_kernel(
    const float* __restrict__ A_dead, const float* __restrict__ w_dec,
    const int* __restrict__ dead_idx, const float* __restrict__ b_pre,
    const double* __restrict__ mu, const double* __restrict__ stdv,
    float* __restrict__ out1)
{
    __shared__ float As[16][64];
    __shared__ float Bs[16][64];
    const int tid = threadIdx.x;
    const int n0 = blockIdx.x * 64;
    const int m0 = blockIdx.y * 64;
    const int tx = tid & 15, ty = tid >> 4;
    const int am = tid >> 2;
    const int ak = (tid & 3) * 4;
    const int bk = tid >> 4;
    const int bn = (tid & 15) * 4;

    float acc[4][4];
#pragma unroll
    for (int i = 0; i < 4; ++i)
#pragma unroll
        for (int j = 0; j < 4; ++j) acc[i][j] = 0.f;

    for (int k0 = 0; k0 < NDEAD; k0 += 16) {
        const float4 a4 = *(const float4*)(A_dead + (size_t)(m0 + am) * NDEAD + k0 + ak);
        As[ak + 0][am] = a4.x;
        As[ak + 1][am] = a4.y;
        As[ak + 2][am] = a4.z;
        As[ak + 3][am] = a4.w;
        const int srow = dead_idx[k0 + bk];
        const float4 b4 = *(const float4*)(w_dec + (size_t)srow * D_MODEL + n0 + bn);
        Bs[bk][bn + 0] = b4.x;
        Bs[bk][bn + 1] = b4.y;
        Bs[bk][bn + 2] = b4.z;
        Bs[bk][bn + 3] = b4.w;
        __syncthreads();
#pragma unroll
        for (int kk = 0; kk < 16; ++kk) {
            float a[4], b[4];
#pragma unroll
            for (int i = 0; i < 4; ++i) a[i] = As[kk][ty * 4 + i];
#pragma unroll
            for (int j = 0; j < 4; ++j) b[j] = Bs[kk][tx * 4 + j];
#pragma unroll
            for (int i = 0; i < 4; ++i)
#pragma unroll
                for (int j = 0; j < 4; ++j) acc[i][j] += a[i] * b[j];
        }
        __syncthreads();
    }
    const float4 bp = *(const float4*)(b_pre + n0 + tx * 4);
#pragma unroll
    for (int i = 0; i < 4; ++i) {
        const int m = m0 + ty * 4 + i;
        const float st = (float)stdv[m];
        const float mm = (float)mu[m];
        float4 o;
        o.x = (acc[i][0] + bp.x) * st + mm;
        o.y = (acc[i][1] + bp.y) * st + mm;
        o.z = (acc[i][2] + bp.z) * st + mm;
        o.w = (acc[i][3] + bp.w) * st + mm;
        *(float4*)(out1 + (size_t)m * D_MODEL + n0 + tx * 4) = o;
    }
}

// -------------------- launch --------------------
extern "C" void kernel_launch(void* const* d_in, const int* in_sizes, int n_in,
                              void* d_out, int out_size, void* d_ws, size_t ws_size,
                              hipStream_t stream)
{
    (void)in_sizes; (void)n_in; (void)out_size;
    const float* x      = (const float*)d_in[0];
    const float* w_enc  = (const float*)d_in[1];
    const float* w_dec  = (const float*)d_in[2];
    const float* b_enc  = (const float*)d_in[3];
    const float* b_pre  = (const float*)d_in[4];
    const unsigned char* dead_mask = (const unsigned char*)d_in[5];
    const int* num_dead = (const int*)d_in[6];
    float* out = (float*)d_out;

    char* base = (char*)d_ws;
    char* w = base;
    auto alloc = [&](size_t bytes) -> char* {
        char* p = w;
        w += (bytes + 255) & ~(size_t)255;
        return p;
    };
    float* p32       = (float*)alloc((size_t)BATCH * D_HIDDEN * 4);   // 256 MB
    double* mu       = (double*)alloc((size_t)BATCH * 8);
    double* stdv     = (double*)alloc((size_t)BATCH * 8);
    double* sinv     = (double*)alloc((size_t)BATCH * 8);
    int* topk_idx    = (int*)alloc((size_t)BATCH * KSEL * 4);
    float* topk_val  = (float*)alloc((size_t)BATCH * KSEL * 4);
    int* dead_idx    = (int*)alloc((size_t)NDEAD * 4);
    int* dead_cnt    = (int*)alloc(256);
    float* A_dead    = (float*)alloc((size_t)BATCH * NDEAD * 4);      // 16 MB
    unsigned short* Ahp = (unsigned short*)alloc((size_t)BATCH * D_MODEL * 2);   // 16 MB
    unsigned short* Amp = (unsigned short*)alloc((size_t)BATCH * D_MODEL * 2);   // 16 MB
    unsigned short* Bhp = (unsigned short*)alloc((size_t)D_HIDDEN * D_MODEL * 2); // 256 MB
    unsigned short* Bmp = (unsigned short*)alloc((size_t)D_HIDDEN * D_MODEL * 2); // 256 MB
    const size_t need_x = (size_t)(w - base);
    const bool presplit = (ws_size >= need_x);

    float* out0 = out;                                   // recons
    float* out1 = out + (size_t)BATCH * D_MODEL;         // auxk
    float* out_last = out + (size_t)2 * BATCH * D_MODEL; // num_dead

    ln_kernel<<<BATCH, 256, 0, stream>>>(x, mu, stdv, sinv);
    dead_scan_kernel<<<1, 64, 0, stream>>>(dead_mask, dead_idx, dead_cnt, num_dead, out_last);
    asplit_kernel<<<BATCH, 256, 0, stream>>>(x, mu, sinv, b_pre, Ahp, Amp);
    if (presplit) {
        bsplit_kernel<<<dim3(D_MODEL / 32, D_HIDDEN / 32), 256, 0, stream>>>(w_enc, Bhp, Bmp);
        enc_mfma_kernel<true><<<dim3(BATCH / 128, D_HIDDEN / 128), 256, 0, stream>>>(
            Ahp, Amp, Bhp, Bmp, w_enc, b_enc, p32);
    } else {
        enc_mfma_kernel<false><<<dim3(BATCH / 128, D_HIDDEN / 128), 256, 0, stream>>>(
            Ahp, Amp, nullptr, nullptr, w_enc, b_enc, p32);
    }
    topk_kernel<<<BATCH, 256, 0, stream>>>(p32, x, mu, sinv, b_pre, w_enc, b_enc, topk_idx, topk_val);
    decode_kernel<<<BATCH, 256, 0, stream>>>(topk_idx, topk_val, w_dec, b_pre, mu, stdv, out0);
    aux_gather_kernel<<<(BATCH * NDEAD) / 256, 256, 0, stream>>>(p32, dead_idx, dead_cnt, A_dead);
    aux_gemm_kernel<<<dim3(D_MODEL / 64, BATCH / 64), 256, 0, stream>>>(
        A_dead, w_dec, dead_idx, b_pre, mu, stdv, out1);
}